// Round 7
// baseline (700.874 us; speedup 1.0000x reference)
//
#include <hip/hip_runtime.h>
#include <math.h>

#define B    4
#define T    16384
#define A    256
#define K    256
#define PAD  128
#define TP   (T + 2*PAD)      // 16640
#define TOUT (TP - K + 1)     // 16385
#define ITERS 16
#define CHUNK 512
#define NCHUNK 33
#define NCP  36               // (fallback) padded per-atom chunk stride
#define TILE 2048
#define NTILE 9
#define NBLK 512              // fallback grid
#define RPPAD 17664           // LDS rp floats (4416 float4); tail zeroed
#define NBLK2 256             // LDS-resident path: 64 blocks/batch, 1 block/CU
#define BPB2 64
#define BARSTRIDE 64
#define DLDS 81920            // dynamic LDS request (>80KB forces 1 block/CU)

#define TAP(acc, s0,s1,s2,s3, dq) { acc = fmaf(s0,(dq).x,acc); acc = fmaf(s1,(dq).y,acc); \
                                    acc = fmaf(s2,(dq).z,acc); acc = fmaf(s3,(dq).w,acc); }

__device__ __forceinline__ void wave_amax(float& bv, int& bi) {
    #pragma unroll
    for (int off = 32; off; off >>= 1) {
        float ov = __shfl_down(bv, off);
        int   oi = __shfl_down(bi, off);
        if (ov > bv || (ov == bv && oi < bi)) { bv = ov; bi = oi; }
    }
}

// ===================== LDS-resident single-kernel path =====================
// Each block: full padded residual rp in LDS + its 4 atoms' normalized taps.
// Per iteration the ONLY global traffic: 32B exchange write + 2KB exchange
// read + 1KB winning-atom taps. Residual update + 1024-output recompute are
// pure LDS. out = x - rp_final (recon eliminated algebraically).
struct KSmem {
    float  rp[RPPAD];         // 70656 B, [16640..17664) zero pad
    float4 dn4[4][64];        // own 4 atoms' taps, 4096 B
    float  chv[4][NCHUNK];    // per-atom chunk maxima
    int    chi[4][NCHUNK];
    float  wv[16]; int wi[16];
    float  fv; int fi;
};

// Per-batch barrier: single counter, 64 arrivals (R4 style; bare dur was
// invariant to barrier flavor in R4/R5/R6, so use the simplest).
__device__ __forceinline__ void gbar64(unsigned* c, unsigned target, int tid) {
    __syncthreads();
    if (tid == 0) {
        __hip_atomic_fetch_add(c, 1u, __ATOMIC_RELEASE, __HIP_MEMORY_SCOPE_AGENT);
        while (__hip_atomic_load(c, __ATOMIC_RELAXED, __HIP_MEMORY_SCOPE_AGENT) < target)
            __builtin_amdgcn_s_sleep(2);
    }
    __syncthreads();
    __builtin_amdgcn_fence(__ATOMIC_ACQUIRE, "agent");
}

// Compute conv outputs [t0, t0+1024) for the block's 4 atoms from LDS rp;
// REPLACE chunk maxima for chunks (t0>>9) and (t0>>9)+1. t0 must be 512-aligned.
__device__ void region_update(KSmem& sm, int t0, int aBase, int tid) {
    const int lane = tid & 63, w = tid >> 6;
    const float4* srp4 = (const float4*)sm.rp;
    float c0[4] = {0,0,0,0}, c1[4] = {0,0,0,0}, c2[4] = {0,0,0,0}, c3[4] = {0,0,0,0};
    int base = (t0 >> 2) + tid;
    float4 p = srp4[base];
    #pragma unroll 4
    for (int kq = 0; kq < 64; kq++) {
        float4 d0 = sm.dn4[0][kq];
        float4 d1 = sm.dn4[1][kq];
        float4 d2 = sm.dn4[2][kq];
        float4 d3 = sm.dn4[3][kq];
        float4 pn = srp4[base + kq + 1];
        TAP(c0[0], p.x,p.y,p.z,p.w, d0); TAP(c0[1], p.y,p.z,p.w,pn.x, d0);
        TAP(c0[2], p.z,p.w,pn.x,pn.y, d0); TAP(c0[3], p.w,pn.x,pn.y,pn.z, d0);
        TAP(c1[0], p.x,p.y,p.z,p.w, d1); TAP(c1[1], p.y,p.z,p.w,pn.x, d1);
        TAP(c1[2], p.z,p.w,pn.x,pn.y, d1); TAP(c1[3], p.w,pn.x,pn.y,pn.z, d1);
        TAP(c2[0], p.x,p.y,p.z,p.w, d2); TAP(c2[1], p.y,p.z,p.w,pn.x, d2);
        TAP(c2[2], p.z,p.w,pn.x,pn.y, d2); TAP(c2[3], p.w,pn.x,pn.y,pn.z, d2);
        TAP(c3[0], p.x,p.y,p.z,p.w, d3); TAP(c3[1], p.y,p.z,p.w,pn.x, d3);
        TAP(c3[2], p.z,p.w,pn.x,pn.y, d3); TAP(c3[3], p.w,pn.x,pn.y,pn.z, d3);
        p = pn;
    }
    int lt = t0 + tid*4;
    float bv0 = -INFINITY, bv1 = -INFINITY, bv2 = -INFINITY, bv3 = -INFINITY;
    int bi0 = 0x7fffffff, bi1 = 0x7fffffff, bi2 = 0x7fffffff, bi3 = 0x7fffffff;
    #pragma unroll
    for (int j = 0; j < 4; j++) {
        int t = lt + j;
        if (t < TOUT) {
            if (c0[j] > bv0) { bv0 = c0[j]; bi0 = (aBase+0)*TOUT + t; }
            if (c1[j] > bv1) { bv1 = c1[j]; bi1 = (aBase+1)*TOUT + t; }
            if (c2[j] > bv2) { bv2 = c2[j]; bi2 = (aBase+2)*TOUT + t; }
            if (c3[j] > bv3) { bv3 = c3[j]; bi3 = (aBase+3)*TOUT + t; }
        }
    }
    wave_amax(bv0, bi0); wave_amax(bv1, bi1); wave_amax(bv2, bi2); wave_amax(bv3, bi3);
    if (lane == 0) {
        sm.wv[0*4+w] = bv0; sm.wi[0*4+w] = bi0;
        sm.wv[1*4+w] = bv1; sm.wi[1*4+w] = bi1;
        sm.wv[2*4+w] = bv2; sm.wi[2*4+w] = bi2;
        sm.wv[3*4+w] = bv3; sm.wi[3*4+w] = bi3;
    }
    __syncthreads();
    // wave w covers outputs [t0+256w, t0+256w+256) -> chunk half h = w>>1
    if (tid < 8) {
        int a = tid >> 1, h = tid & 1;
        float v0 = sm.wv[a*4 + 2*h];   int i0 = sm.wi[a*4 + 2*h];
        float v1 = sm.wv[a*4 + 2*h+1]; int i1 = sm.wi[a*4 + 2*h+1];
        if (v1 > v0 || (v1 == v0 && i1 < i0)) { v0 = v1; i0 = i1; }
        int chunk = (t0 >> 9) + h;
        if (chunk < NCHUNK) { sm.chv[a][chunk] = v0; sm.chi[a][chunk] = i0; }
    }
    __syncthreads();
}

// Refresh per-atom best over all 33 chunks; write to exchange buffers.
__device__ __forceinline__ void best_write(KSmem& sm, int a0, int b, int tid,
                                           float* __restrict__ abv, int* __restrict__ abi) {
    const int lane = tid & 63, w = tid >> 6;  // wave w -> atom w
    float bv = -INFINITY; int bi = 0x7fffffff;
    if (lane < NCHUNK) { bv = sm.chv[w][lane]; bi = sm.chi[w][lane]; }
    wave_amax(bv, bi);
    if (lane == 0) { abv[b*A + a0*4 + w] = bv; abi[b*A + a0*4 + w] = bi; }
}

__device__ __forceinline__ void pick(KSmem& sm, int b, int tid,
                                     const float* __restrict__ avc, const int* __restrict__ aic) {
    const int lane = tid & 63, w = tid >> 6;
    float bv = avc[b*A + tid]; int bi = aic[b*A + tid];
    wave_amax(bv, bi);
    if (lane == 0) { sm.wv[w] = bv; sm.wi[w] = bi; }
    __syncthreads();
    if (tid == 0) {
        bv = sm.wv[0]; bi = sm.wi[0];
        for (int j = 1; j < 4; j++)
            if (sm.wv[j] > bv || (sm.wv[j] == bv && sm.wi[j] < bi)) { bv = sm.wv[j]; bi = sm.wi[j]; }
        sm.fv = bv; sm.fi = bi;
    }
    __syncthreads();
}

__global__ void __launch_bounds__(256, 1)
k_coop(const float* __restrict__ x, const float* __restrict__ d, float* __restrict__ out,
       float* __restrict__ dn,
       float* __restrict__ abv0, int* __restrict__ abi0,
       float* __restrict__ abv1, int* __restrict__ abi1, unsigned* __restrict__ bar) {
    extern __shared__ char raw[];
    KSmem& sm = *(KSmem*)raw;
    const int bid = blockIdx.x, tid = threadIdx.x;
    const int a0 = bid & (BPB2-1), b = bid >> 6;
    const int lane = tid & 63, w = tid >> 6;
    unsigned* cb = bar + b*BARSTRIDE;

    // ---- init: x -> LDS rp (padded, zero tail) ----
    {
        const float4* xb4 = (const float4*)(x + (size_t)b*T);
        float4* rp4w = (float4*)sm.rp;
        for (int i = tid; i < RPPAD/4; i += 256) {
            float4 v = {0.f,0.f,0.f,0.f};
            if (i >= PAD/4 && i < (PAD+T)/4) v = xb4[i - PAD/4];
            rp4w[i] = v;
        }
    }
    // ---- normalize own 4 atoms into LDS + global dn (redundant identical) ----
    #pragma unroll
    for (int s = 0; s < 4; s++) {
        int atom = a0*4 + s;
        float v = d[atom*K + tid];
        float sq = v*v;
        #pragma unroll
        for (int off = 32; off; off >>= 1) sq += __shfl_down(sq, off);
        if (lane == 0) sm.wv[w] = sq;
        __syncthreads();
        float norm = sqrtf(sm.wv[0] + sm.wv[1] + sm.wv[2] + sm.wv[3]) + 1e-12f;
        float nv = v / norm;
        ((float*)&sm.dn4[s][0])[tid] = nv;
        dn[atom*K + tid] = nv;
        __syncthreads();
    }
    // ---- full conv from LDS (17 passes of 1024 outputs) ----
    for (int p = 0; p < 17; p++) region_update(sm, p*1024, a0*4, tid);
    best_write(sm, a0, b, tid, abv0, abi0);
    unsigned gen = 1; gbar64(cb, gen*BPB2, tid);

    const float* avc = abv0; const int* aic = abi0;
    float* avn = abv1; int* ain = abi1;
    for (int it = 0; it < ITERS-1; it++) {
        pick(sm, b, tid, avc, aic);
        float val = sm.fv; int idx = sm.fi;
        int atom = idx / TOUT, pos = idx - atom*TOUT;
        float ds = dn[atom*K + tid];            // winning atom taps (global, read-only)
        sm.rp[pos + tid] -= val * ds;           // local LDS residual update
        __syncthreads();
        int lo = pos - (K-1); if (lo < 0) lo = 0;
        int t0 = (lo >> 9) * 512;               // 2-chunk region covers change window
        region_update(sm, t0, a0*4, tid);
        best_write(sm, a0, b, tid, avn, ain);
        { const float* t1 = avc; avc = avn; avn = (float*)t1; }
        { const int*   t2 = aic; aic = ain; ain = (int*)t2; }
        gen++; gbar64(cb, gen*BPB2, tid);
    }
    // ---- final pick + update + out (only blocks a0==0; others exit) ----
    if (a0 == 0) {
        pick(sm, b, tid, avc, aic);
        float val = sm.fv; int idx = sm.fi;
        int atom = idx / TOUT, pos = idx - atom*TOUT;
        float ds = dn[atom*K + tid];
        sm.rp[pos + tid] -= val * ds;
        __syncthreads();
        const float4* xb4 = (const float4*)(x + (size_t)b*T);
        float4* o4 = (float4*)(out + (size_t)b*T);
        for (int i = tid; i < T/4; i += 256) {
            float4 xv = xb4[i];
            float4 rv = *(const float4*)&sm.rp[PAD + i*4];
            float4 ov; ov.x = xv.x - rv.x; ov.y = xv.y - rv.y;
            ov.z = xv.z - rv.z; ov.w = xv.w - rv.w;
            o4[i] = ov;
        }
    }
}

// ===================== fallback path (unchanged from R6, race-free) =====================
struct Smem {
    float rp[TILE + K + 16];
    float dnA[K];
    float dnB[K];
    float dnsel[K];
    float wv[16]; int wi[16];
    float fv; int fi;
};

__device__ __forceinline__ void dev_norm(int a0, int tid, const float* __restrict__ d,
                                         float* __restrict__ dn, Smem& sm) {
    int lane = tid & 63, w = tid >> 6;
    #pragma unroll
    for (int s = 0; s < 2; s++) {
        int atom = a0*2 + s;
        float v = d[atom*K + tid];
        float sq = v*v;
        #pragma unroll
        for (int off = 32; off; off >>= 1) sq += __shfl_down(sq, off);
        if (lane == 0) sm.wv[w] = sq;
        __syncthreads();
        float norm = sqrtf(sm.wv[0] + sm.wv[1] + sm.wv[2] + sm.wv[3]) + 1e-12f;
        dn[atom*K + tid] = v / norm;
        __syncthreads();
    }
}

__device__ __forceinline__ void dev_init(int a0, int b, int tid, const float* __restrict__ x,
                                         float* __restrict__ rp, float* __restrict__ recon) {
    int i = a0*256 + tid;
    if (i < TP) {
        float v = (i >= PAD && i < PAD + T) ? x[b*T + (i - PAD)] : 0.f;
        rp[(size_t)b*TP + i] = v;
        recon[(size_t)b*TP + i] = 0.f;
    }
}

__device__ void dev_conv(int a0, int b, int tid, const float* __restrict__ rp,
                         const float* __restrict__ dn,
                         float* __restrict__ segval, int* __restrict__ segidx,
                         float* __restrict__ abv, int* __restrict__ abi, Smem& sm) {
    const int aA = a0*2, aB = a0*2 + 1;
    const int lane = tid & 63, w = tid >> 6;
    sm.dnA[tid] = dn[aA*K + tid];
    sm.dnB[tid] = dn[aB*K + tid];
    const float4* rp4 = (const float4*)(rp + (size_t)b*TP);

    for (int tile = 0; tile < NTILE; tile++) {
        int t0 = tile * TILE;
        __syncthreads();
        float4* s4 = (float4*)sm.rp;
        for (int i = tid; i < 580; i += 256) {
            int g = t0/4 + i;
            float4 v = {0.f,0.f,0.f,0.f};
            if (g*4 < TP) v = rp4[g];
            s4[i] = v;
        }
        __syncthreads();
        const float4* srp4 = (const float4*)sm.rp;
        const float4* dA4  = (const float4*)sm.dnA;
        const float4* dB4  = (const float4*)sm.dnB;
        float accA0[4] = {0,0,0,0}, accA1[4] = {0,0,0,0};
        float accB0[4] = {0,0,0,0}, accB1[4] = {0,0,0,0};
        float4 p = srp4[tid];
        float4 q = srp4[tid + 256];
        #pragma unroll 4
        for (int kq = 0; kq < 64; kq++) {
            float4 dA = dA4[kq];
            float4 dB = dB4[kq];
            float4 pn = srp4[tid + kq + 1];
            float4 qn = srp4[tid + 256 + kq + 1];
            TAP(accA0[0], p.x,p.y,p.z,p.w, dA); TAP(accA0[1], p.y,p.z,p.w,pn.x, dA);
            TAP(accA0[2], p.z,p.w,pn.x,pn.y, dA); TAP(accA0[3], p.w,pn.x,pn.y,pn.z, dA);
            TAP(accB0[0], p.x,p.y,p.z,p.w, dB); TAP(accB0[1], p.y,p.z,p.w,pn.x, dB);
            TAP(accB0[2], p.z,p.w,pn.x,pn.y, dB); TAP(accB0[3], p.w,pn.x,pn.y,pn.z, dB);
            TAP(accA1[0], q.x,q.y,q.z,q.w, dA); TAP(accA1[1], q.y,q.z,q.w,qn.x, dA);
            TAP(accA1[2], q.z,q.w,qn.x,qn.y, dA); TAP(accA1[3], q.w,qn.x,qn.y,qn.z, dA);
            TAP(accB1[0], q.x,q.y,q.z,q.w, dB); TAP(accB1[1], q.y,q.z,q.w,qn.x, dB);
            TAP(accB1[2], q.z,q.w,qn.x,qn.y, dB); TAP(accB1[3], q.w,qn.x,qn.y,qn.z, dB);
            p = pn; q = qn;
        }
        int lt = tid * 4;
        float bvA0 = -INFINITY, bvA1 = -INFINITY, bvB0 = -INFINITY, bvB1 = -INFINITY;
        int biA0 = 0x7fffffff, biA1 = 0x7fffffff, biB0 = 0x7fffffff, biB1 = 0x7fffffff;
        #pragma unroll
        for (int j = 0; j < 4; j++) {
            int t = t0 + lt + j;
            if (t < TOUT) {
                if (accA0[j] > bvA0) { bvA0 = accA0[j]; biA0 = aA*TOUT + t; }
                if (accB0[j] > bvB0) { bvB0 = accB0[j]; biB0 = aB*TOUT + t; }
            }
            int t1 = t0 + 1024 + lt + j;
            if (t1 < TOUT) {
                if (accA1[j] > bvA1) { bvA1 = accA1[j]; biA1 = aA*TOUT + t1; }
                if (accB1[j] > bvB1) { bvB1 = accB1[j]; biB1 = aB*TOUT + t1; }
            }
        }
        wave_amax(bvA0, biA0); wave_amax(bvA1, biA1);
        wave_amax(bvB0, biB0); wave_amax(bvB1, biB1);
        if (lane == 0) {
            sm.wv[w]    = bvA0; sm.wi[w]    = biA0;
            sm.wv[4+w]  = bvA1; sm.wi[4+w]  = biA1;
            sm.wv[8+w]  = bvB0; sm.wi[8+w]  = biB0;
            sm.wv[12+w] = bvB1; sm.wi[12+w] = biB1;
        }
        __syncthreads();
        if (tid < 4) {
            float v0 = sm.wv[2*tid];   int i0 = sm.wi[2*tid];
            float v1 = sm.wv[2*tid+1]; int i1 = sm.wi[2*tid+1];
            if (v1 > v0 || (v1 == v0 && i1 < i0)) { v0 = v1; i0 = i1; }
            int chunk = tile*4 + tid;
            if (chunk < NCHUNK) {
                segval[((size_t)b*A + aA)*NCP + chunk] = v0;
                segidx[((size_t)b*A + aA)*NCP + chunk] = i0;
            }
        } else if (tid >= 64 && tid < 68) {
            int c = tid - 64;
            float v0 = sm.wv[8+2*c];   int i0 = sm.wi[8+2*c];
            float v1 = sm.wv[8+2*c+1]; int i1 = sm.wi[8+2*c+1];
            if (v1 > v0 || (v1 == v0 && i1 < i0)) { v0 = v1; i0 = i1; }
            int chunk = tile*4 + c;
            if (chunk < NCHUNK) {
                segval[((size_t)b*A + aB)*NCP + chunk] = v0;
                segidx[((size_t)b*A + aB)*NCP + chunk] = i0;
            }
        }
    }
    __syncthreads();
    if (w < 2) {
        int atom = (w == 0) ? aA : aB;
        float bv = -INFINITY; int bi = 0x7fffffff;
        if (lane < NCHUNK) {
            bv = segval[((size_t)b*A + atom)*NCP + lane];
            bi = segidx[((size_t)b*A + atom)*NCP + lane];
        }
        wave_amax(bv, bi);
        if (lane == 0) { abv[b*A + atom] = bv; abi[b*A + atom] = bi; }
    }
}

__device__ void dev_iter(int a0, int b, int tid, int last,
                         const float* __restrict__ avc, const int* __restrict__ aic,
                         float* __restrict__ avn, int* __restrict__ ain,
                         const float* __restrict__ rin, float* __restrict__ rout,
                         float* __restrict__ recon, const float* __restrict__ dn,
                         float* __restrict__ segval, int* __restrict__ segidx, Smem& sm) {
    const int aA = a0*2, aB = a0*2 + 1;
    const int lane = tid & 63, w = tid >> 6;

    float bv0 = avc[b*A + tid]; int bi0 = aic[b*A + tid];
    const float4* rin4 = (const float4*)(rin + (size_t)b*TP);
    const int icopy = a0*256 + tid;
    const bool docopy = (!last) && (icopy < TP/4);
    float4 vcopy = {0.f,0.f,0.f,0.f};
    if (docopy) vcopy = rin4[icopy];
    sm.dnA[tid] = dn[aA*K + tid];
    sm.dnB[tid] = dn[aB*K + tid];

    {
        float bv = bv0; int bi = bi0;
        wave_amax(bv, bi);
        if (lane == 0) { sm.wv[w] = bv; sm.wi[w] = bi; }
        __syncthreads();
        if (tid == 0) {
            bv = sm.wv[0]; bi = sm.wi[0];
            for (int j = 1; j < 4; j++)
                if (sm.wv[j] > bv || (sm.wv[j] == bv && sm.wi[j] < bi)) { bv = sm.wv[j]; bi = sm.wi[j]; }
            sm.fv = bv; sm.fi = bi;
        }
        __syncthreads();
    }
    float val = sm.fv; int idx = sm.fi;
    int atom = idx / TOUT, pos = idx - atom*TOUT;
    sm.dnsel[tid] = dn[atom*K + tid];

    int lo = pos - (K-1); if (lo < 0) lo = 0;
    int c_lo = lo >> 9;
    int tbase = c_lo * CHUNK;

    if (!last) {
        float4* s4 = (float4*)sm.rp;
        for (int i = tid; i < 324; i += 256) {
            int g = tbase/4 + i;
            float4 v = {0.f,0.f,0.f,0.f};
            if (g*4 < TP) v = rin4[g];
            s4[i] = v;
        }
    }
    __syncthreads();
    if (docopy) {
        float4* rout4 = (float4*)(rout + (size_t)b*TP);
        float4 v = vcopy;
        int o = icopy*4 - pos;
        if (o > -4 && o < K) {
            if (o+0 >= 0 && o+0 < K) v.x -= val * sm.dnsel[o+0];
            if (o+1 >= 0 && o+1 < K) v.y -= val * sm.dnsel[o+1];
            if (o+2 >= 0 && o+2 < K) v.z -= val * sm.dnsel[o+2];
            if (o+3 >= 0 && o+3 < K) v.w -= val * sm.dnsel[o+3];
        }
        rout4[icopy] = v;
    }
    if (a0 == 0) {
        recon[(size_t)b*TP + pos + tid] += val * sm.dnsel[tid];
    }
    if (last) return;

    sm.rp[pos + tid - tbase] -= val * sm.dnsel[tid];
    __syncthreads();

    const float4* srp4 = (const float4*)sm.rp;
    const float4* dA4  = (const float4*)sm.dnA;
    const float4* dB4  = (const float4*)sm.dnB;
    float cA[4] = {0,0,0,0}, cB[4] = {0,0,0,0};
    float4 p = srp4[tid];
    #pragma unroll 4
    for (int kq = 0; kq < 64; kq++) {
        float4 dA = dA4[kq];
        float4 dB = dB4[kq];
        float4 pn = srp4[tid + kq + 1];
        TAP(cA[0], p.x,p.y,p.z,p.w, dA); TAP(cA[1], p.y,p.z,p.w,pn.x, dA);
        TAP(cA[2], p.z,p.w,pn.x,pn.y, dA); TAP(cA[3], p.w,pn.x,pn.y,pn.z, dA);
        TAP(cB[0], p.x,p.y,p.z,p.w, dB); TAP(cB[1], p.y,p.z,p.w,pn.x, dB);
        TAP(cB[2], p.z,p.w,pn.x,pn.y, dB); TAP(cB[3], p.w,pn.x,pn.y,pn.z, dB);
        p = pn;
    }
    int lt = tid * 4;
    float bvA = -INFINITY, bvB = -INFINITY;
    int biA = 0x7fffffff, biB = 0x7fffffff;
    #pragma unroll
    for (int j = 0; j < 4; j++) {
        int t = tbase + lt + j;
        if (t < TOUT) {
            if (cA[j] > bvA) { bvA = cA[j]; biA = aA*TOUT + t; }
            if (cB[j] > bvB) { bvB = cB[j]; biB = aB*TOUT + t; }
        }
    }
    wave_amax(bvA, biA); wave_amax(bvB, biB);
    if (lane == 0) { sm.wv[w] = bvA; sm.wi[w] = biA; sm.wv[8+w] = bvB; sm.wi[8+w] = biB; }
    __syncthreads();
    if (tid < 2) {
        float v0 = sm.wv[2*tid];   int i0 = sm.wi[2*tid];
        float v1 = sm.wv[2*tid+1]; int i1 = sm.wi[2*tid+1];
        if (v1 > v0 || (v1 == v0 && i1 < i0)) { v0 = v1; i0 = i1; }
        int chunk = c_lo + tid;
        if (chunk < NCHUNK) {
            segval[((size_t)b*A + aA)*NCP + chunk] = v0;
            segidx[((size_t)b*A + aA)*NCP + chunk] = i0;
        }
    } else if (tid >= 64 && tid < 66) {
        int c = tid - 64;
        float v0 = sm.wv[8+2*c];   int i0 = sm.wi[8+2*c];
        float v1 = sm.wv[8+2*c+1]; int i1 = sm.wi[8+2*c+1];
        if (v1 > v0 || (v1 == v0 && i1 < i0)) { v0 = v1; i0 = i1; }
        int chunk = c_lo + c;
        if (chunk < NCHUNK) {
            segval[((size_t)b*A + aB)*NCP + chunk] = v0;
            segidx[((size_t)b*A + aB)*NCP + chunk] = i0;
        }
    }
    __syncthreads();
    if (w < 2) {
        int at = (w == 0) ? aA : aB;
        float bv = -INFINITY; int bi = 0x7fffffff;
        if (lane < NCHUNK) {
            bv = segval[((size_t)b*A + at)*NCP + lane];
            bi = segidx[((size_t)b*A + at)*NCP + lane];
        }
        wave_amax(bv, bi);
        if (lane == 0) { avn[b*A + at] = bv; ain[b*A + at] = bi; }
    }
}

__global__ void __launch_bounds__(256) k_f_norm_init(const float* x, const float* d,
                                                     float* dn, float* rp0, float* recon) {
    __shared__ Smem sm;
    dev_norm(blockIdx.x & 127, threadIdx.x, d, dn, sm);
    dev_init(blockIdx.x & 127, blockIdx.x >> 7, threadIdx.x, x, rp0, recon);
}
__global__ void __launch_bounds__(256, 2) k_f_conv(const float* rp, const float* dn,
                                                   float* segval, int* segidx,
                                                   float* abv, int* abi) {
    __shared__ Smem sm;
    dev_conv(blockIdx.x & 127, blockIdx.x >> 7, threadIdx.x, rp, dn, segval, segidx, abv, abi, sm);
}
__global__ void __launch_bounds__(256, 2) k_f_iter(int last,
                                                   const float* avc, const int* aic,
                                                   float* avn, int* ain,
                                                   const float* rin, float* rout,
                                                   float* recon, const float* dn,
                                                   float* segval, int* segidx) {
    __shared__ Smem sm;
    dev_iter(blockIdx.x & 127, blockIdx.x >> 7, threadIdx.x, last,
             avc, aic, avn, ain, rin, rout, recon, dn, segval, segidx, sm);
}
__global__ void k_f_out(const float* recon, float* out) {
    int i = blockIdx.x * blockDim.x + threadIdx.x;
    if (i >= B*T) return;
    int b = i / T, t = i - b*T;
    out[i] = recon[(size_t)b*TP + PAD + t];
}

extern "C" void kernel_launch(void* const* d_in, const int* in_sizes, int n_in,
                              void* d_out, int out_size, void* d_ws, size_t ws_size,
                              hipStream_t stream) {
    const float* x = (const float*)d_in[0];
    const float* d = (const float*)d_in[1];
    float* out = (float*)d_out;

    float* ws     = (float*)d_ws;
    float* dn     = ws;                                   // A*K
    float* rp0    = dn  + (size_t)A*K;                    // B*TP (fallback)
    float* rp1    = rp0 + (size_t)B*TP;                   // B*TP (fallback)
    float* recon  = rp1 + (size_t)B*TP;                   // B*TP (fallback)
    float* segval = recon + (size_t)B*TP;                 // B*A*NCP (fallback)
    int*   segidx = (int*)(segval + (size_t)B*A*NCP);     // B*A*NCP (fallback)
    float* abv0   = (float*)(segidx + (size_t)B*A*NCP);   // B*A
    float* abv1   = abv0 + (size_t)B*A;                   // B*A
    int*   abi0   = (int*)(abv1 + (size_t)B*A);           // B*A
    int*   abi1   = abi0 + (size_t)B*A;                   // B*A
    unsigned* bar = (unsigned*)(abi1 + (size_t)B*A);      // per-batch counters

    // LDS-resident path feasibility: needs 256 co-resident blocks with DLDS
    // dynamic LDS (>64KB -> set the attribute first, then occupancy-check).
    (void)hipFuncSetAttribute((const void*)k_coop,
                              hipFuncAttributeMaxDynamicSharedMemorySize, DLDS);
    int nb = 0, ncu = 0;
    hipError_t e1 = hipOccupancyMaxActiveBlocksPerMultiprocessor(&nb, (const void*)k_coop,
                                                                 256, DLDS);
    hipError_t e2 = hipDeviceGetAttribute(&ncu, hipDeviceAttributeMultiprocessorCount, 0);
    bool coop = (e1 == hipSuccess && e2 == hipSuccess && nb > 0 && ncu > 0 &&
                 (long)nb * ncu >= NBLK2);
    if (coop) {
        (void)hipMemsetAsync(bar, 0, B*BARSTRIDE*sizeof(unsigned), stream);
        hipLaunchKernelGGL(k_coop, dim3(NBLK2), dim3(256), DLDS, stream,
                           x, d, out, dn, abv0, abi0, abv1, abi1, bar);
        return;
    }
    // fallback: separate launches, double-buffered (race-free)
    k_f_norm_init<<<NBLK, 256, 0, stream>>>(x, d, dn, rp0, recon);
    k_f_conv<<<NBLK, 256, 0, stream>>>(rp0, dn, segval, segidx, abv0, abi0);
    float* rbuf[2] = {rp0, rp1};
    float* av[2]   = {abv0, abv1};
    int*   ai[2]   = {abi0, abi1};
    for (int it = 0; it < ITERS; it++) {
        k_f_iter<<<NBLK, 256, 0, stream>>>(it == ITERS-1 ? 1 : 0,
                                           av[it & 1], ai[it & 1],
                                           av[(it + 1) & 1], ai[(it + 1) & 1],
                                           rbuf[it & 1], rbuf[(it + 1) & 1],
                                           recon, dn, segval, segidx);
    }
    k_f_out<<<(B*T + 255)/256, 256, 0, stream>>>(recon, out);
}